// Round 20
// baseline (39.620 us; speedup 1.0000x reference)
//
#include <hip/hip_runtime.h>
#include <hip/hip_bf16.h>

#define BB 8
#define NN 256
#define LC 128

typedef short short8 __attribute__((ext_vector_type(8)));
typedef float f32x4 __attribute__((ext_vector_type(4)));

union U8 { short8 s; unsigned u[4]; };

__device__ inline unsigned pkbf(float a, float b){
    __hip_bfloat162 h = __float22bfloat162_rn(make_float2(a, b));
    union { __hip_bfloat162 h2; unsigned u; } cv; cv.h2 = h; return cv.u;
}

// stage alpha*Y (bf16) for one j into a slab [msl][j], stride 264
__device__ inline void stage_aY(short* __restrict__ slab, int j, float a,
                                float dx, float dy, float dz, float r2)
{
    const float ir = rsqrtf(r2);
    const float ux = dx*ir, uy = dy*ir, uz = dz*ir;
    const float X2 = ux*ux, Y2 = uy*uy, Z2 = uz*uz;
    const float y0  = 0.28209479f;
    const float y1  = 0.48860251f*uy, y2 = 0.48860251f*uz, y3 = 0.48860251f*ux;
    const float y4  = 1.09254843f*ux*uy;
    const float y5  = 1.09254843f*uy*uz;
    const float y6  = 0.31539157f*(3.f*Z2 - 1.f);
    const float y7  = 1.09254843f*ux*uz;
    const float y8  = 0.54627422f*(X2 - Y2);
    const float y9  = 0.59004359f*uy*(3.f*X2 - Y2);
    const float y10 = 2.89061144f*ux*uy*uz;
    const float y11 = 0.45704579f*uy*(5.f*Z2 - 1.f);
    const float y12 = 0.37317633f*uz*(5.f*Z2 - 3.f);
    const float y13 = 0.45704579f*ux*(5.f*Z2 - 1.f);
    const float y14 = 1.44530572f*uz*(X2 - Y2);
    const float y15 = 0.59004359f*ux*(X2 - 3.f*Y2);
    #define ST2(mm, va, vb) { unsigned uu = pkbf((va)*a, (vb)*a); \
        slab[(mm)*264 + j] = (short)(uu & 0xffff); slab[(mm+1)*264 + j] = (short)(uu >> 16); }
    ST2(0,  y0,  y1)  ST2(2,  y2,  y3)
    ST2(4,  y4,  y5)  ST2(6,  y6,  y7)
    ST2(8,  y8,  y9)  ST2(10, y10, y11)
    ST2(12, y12, y13) ST2(14, y14, y15)
    #undef ST2
}

// ---------------- Kernel B: 2 waves per i — j-split prologue, col-split loop ----------------
// grid = BB*128 blocks; block = 4 waves = 2 i's x 2 roles.
__global__ __launch_bounds__(256) void so3_main(
    const float* __restrict__ xg,     // (B,N,4)
    const float* __restrict__ Wq,     // (4,32)
    const float* __restrict__ Wk,     // (4,32)
    const float* __restrict__ Wv,     // (L,4,32)
    const float* __restrict__ Rw1,    // (32)
    const float* __restrict__ Rb1,    // (32)
    const float* __restrict__ Rw2,    // (32,128)
    const float* __restrict__ Rb2,    // (128)
    float* __restrict__ invg)         // (B,N,128)
{
    const int tid = threadIdx.x;          // 0..255
    const int blk = blockIdx.x;           // b*128 + pair
    const int b = blk >> 7;
    const int i0 = (blk & 127) << 1;
    const int rowbase = b * NN;
    const int lane = tid & 63;
    const int w = tid >> 6;               // wave 0..3
    const int iw = w >> 1;                // which i of the pair
    const int h = w & 1;                  // role: j-half (prologue) / col-half (loop)
    const int pw = w ^ 1;                 // partner wave (same i)
    const int n = lane & 15;
    const int g = lane >> 4;
    const int kbase = g * 8;
    const int i = i0 + iw;
    const int jb = h * 128;               // this wave's j-half base

    __shared__ __align__(16) float xs[NN*4];   // 4 KB
    __shared__ short xsbf[NN*4];               // 2 KB
    __shared__ short slab2[2][16*264];         // per-i shared slabs (16.9 KB)
    __shared__ float r_sh[2][NN];              // per-i r values (2 KB)
    __shared__ float evs[2][NN];               // per-i raw ev (2 KB)
    __shared__ float pex[4][2];                // per-wave {max, sum}

    // ---- block-cooperative x staging ----
    const float4 x4 = *(const float4*)&xg[(rowbase + tid)*4];
    *(float4*)&xs[tid*4] = x4;
    {
        uint2 xb;
        xb.x = pkbf(x4.x, x4.y);
        xb.y = pkbf(x4.z, x4.w);
        *(uint2*)&xsbf[tid*4] = xb;
    }
    const float4 xi = *(const float4*)&xg[(rowbase + i)*4];

    // ---- per-wave m[d] (shfl only; duplicated across the i's wave pair — cheap) ----
    float md0, md1, md2, md3;
    {
        const int c = lane & 31;
        const float qc = xi.x*Wq[c] + xi.y*Wq[32+c] + xi.z*Wq[64+c] + xi.w*Wq[96+c];
        md0 = qc*Wk[c]; md1 = qc*Wk[32+c]; md2 = qc*Wk[64+c]; md3 = qc*Wk[96+c];
        #pragma unroll
        for (int off = 16; off >= 1; off >>= 1) {
            md0 += __shfl_xor(md0, off);
            md1 += __shfl_xor(md1, off);
            md2 += __shfl_xor(md2, off);
            md3 += __shfl_xor(md3, off);
        }
        const float lscale = 0.17677669529663687f;  // 1/sqrt(32)
        md0 *= lscale; md1 *= lscale; md2 *= lscale; md3 *= lscale;
    }

    __syncthreads();   // barrier #1: xs/xsbf ready

    // ---- j-split sweep: this wave covers j = jb + 16s + n, s=0..7 ----
    float mx, es;
    {
        float lgv[8];
        #pragma unroll
        for (int s = 0; s < 8; ++s) {
            const int j = jb + 16*s + n;
            const float4 xa = *(const float4*)&xs[j*4];
            const float ddx = xa.x - xi.x, ddy = xa.y - xi.y, ddz = xa.z - xi.z;
            const float r2 = ddx*ddx + ddy*ddy + ddz*ddz + 1e-8f;
            r_sh[iw][j] = sqrtf(r2);
            lgv[s] = md0*xa.x + md1*xa.y + md2*xa.z + md3*xa.w;
        }
        mx = lgv[0];
        #pragma unroll
        for (int s = 1; s < 8; ++s) mx = fmaxf(mx, lgv[s]);
        #pragma unroll
        for (int off = 1; off <= 8; off <<= 1) mx = fmaxf(mx, __shfl_xor(mx, off));
        es = 0.f;
        #pragma unroll
        for (int s = 0; s < 8; ++s) {
            const float e = __expf(lgv[s] - mx);
            evs[iw][jb + 16*s + n] = e;
            es += e;
        }
        #pragma unroll
        for (int off = 1; off <= 8; off <<= 1) es += __shfl_xor(es, off);
        if (lane == 0) { pex[w][0] = mx; pex[w][1] = es; }
    }

    __syncthreads();   // barrier #2: r_sh/evs/pex ready

    // ---- cross-wave softmax combine (wave-uniform) ----
    const float mxp = pex[pw][0], esp = pex[pw][1];
    const float M = fmaxf(mx, mxp);
    const float S = es*__expf(mx - M) + esp*__expf(mxp - M);
    const float scale = __expf(mx - M) / S;

    // ---- stage this wave's j-half into the SHARED per-i slab ----
    short* slab = &slab2[iw][0];
    #pragma unroll
    for (int e = 0; e < 2; ++e) {
        const int j = jb + 32*g + 16*e + n;
        const float a = evs[iw][j] * scale;
        const float4 xa = *(const float4*)&xs[j*4];
        const float ddx = xa.x - xi.x, ddy = xa.y - xi.y, ddz = xa.z - xi.z;
        const float r2 = ddx*ddx + ddy*ddy + ddz*ddz + 1e-8f;
        stage_aY(slab, j, a, ddx, ddy, ddz, r2);
    }

    // ---- r for ALL 256 j from shared (s=0..15) ----
    float r_reg[16];
    #pragma unroll
    for (int s = 0; s < 16; ++s) r_reg[s] = r_sh[iw][16*s + n];

    float rw1q[8], rb1q[8];
    #pragma unroll
    for (int q = 0; q < 8; ++q) { rw1q[q] = Rw1[kbase+q]; rb1q[q] = Rb1[kbase+q]; }

    // ---- fragments for OWN col-half only ----
    short8 bfrag[4], bv[4];
    float rb2v[4];
    #pragma unroll
    for (int t4 = 0; t4 < 4; ++t4) {
        const int col = h*64 + t4*16 + n;
        U8 bf;
        #pragma unroll
        for (int qq = 0; qq < 4; ++qq)
            bf.u[qq] = pkbf(Rw2[(kbase+2*qq)*LC + col], Rw2[(kbase+2*qq+1)*LC + col]);
        bfrag[t4] = bf.s;
        rb2v[t4] = Rb2[col];
        U8 z; z.u[0] = 0; z.u[1] = 0; z.u[2] = 0; z.u[3] = 0;
        if (g == 0) {
            const int l = (h*64 + t4*16) >> 5;
            const int cc = (t4 & 1)*16 + n;
            z.u[0] = pkbf(Wv[l*128 + cc],      Wv[l*128 + 32 + cc]);
            z.u[1] = pkbf(Wv[l*128 + 64 + cc], Wv[l*128 + 96 + cc]);
        }
        bv[t4] = z.s;
    }

    __syncthreads();   // barrier #3: both slab halves staged

    const int boff = n*264 + 4*g;
    const f32x4 vzero = {0.f, 0.f, 0.f, 0.f};
    f32x4 acc[4] = {};

    // ---- loop: own col-half, ALL 8 j-tiles, barrier-free per-wave ----
    #pragma unroll
    for (int tt = 0; tt < 8; ++tt) {
        const int j0 = 32*tt;

        const uint2 blo = *(const uint2*)&slab[boff + j0];
        const uint2 bhi = *(const uint2*)&slab[boff + j0 + 16];
        U8 bf2;
        bf2.u[0] = blo.x; bf2.u[1] = blo.y; bf2.u[2] = bhi.x; bf2.u[3] = bhi.y;

        uint2 P[2][4];
        #pragma unroll
        for (int jh = 0; jh < 2; ++jh) {
            const float rj = r_reg[2*tt + jh];
            U8 af;
            #pragma unroll
            for (int qq = 0; qq < 4; ++qq) {
                const float h0 = fmaxf(rj*rw1q[2*qq]   + rb1q[2*qq],   0.f);
                const float h1 = fmaxf(rj*rw1q[2*qq+1] + rb1q[2*qq+1], 0.f);
                af.u[qq] = pkbf(h0, h1);
            }
            U8 afV; afV.u[0] = 0; afV.u[1] = 0; afV.u[2] = 0; afV.u[3] = 0;
            if (g == 0) {
                const uint2 xb = *(const uint2*)&xsbf[(j0 + 16*jh + n)*4];
                afV.u[0] = xb.x; afV.u[1] = xb.y;
            }
            #pragma unroll
            for (int t4 = 0; t4 < 4; ++t4) {
                f32x4 d  = __builtin_amdgcn_mfma_f32_16x16x32_bf16(af.s,  bfrag[t4], vzero, 0, 0, 0);
                f32x4 vv = __builtin_amdgcn_mfma_f32_16x16x32_bf16(afV.s, bv[t4],    vzero, 0, 0, 0);
                P[jh][t4].x = pkbf((d[0]+rb2v[t4])*vv[0], (d[1]+rb2v[t4])*vv[1]);
                P[jh][t4].y = pkbf((d[2]+rb2v[t4])*vv[2], (d[3]+rb2v[t4])*vv[3]);
            }
        }

        #pragma unroll
        for (int t4 = 0; t4 < 4; ++t4) {
            U8 a2;
            a2.u[0] = P[0][t4].x; a2.u[1] = P[0][t4].y;
            a2.u[2] = P[1][t4].x; a2.u[3] = P[1][t4].y;
            acc[t4] = __builtin_amdgcn_mfma_f32_16x16x32_bf16(a2.s, bf2.s, acc[t4], 0, 0, 0);
        }
    }

    // ---- per-wave epilogue: own col-half, direct store (acc complete over j) ----
    #pragma unroll
    for (int t4 = 0; t4 < 4; ++t4) {
        const int l = h*2 + (t4 >> 1);
        const int lo = l*l, hi = l*l + 2*l;
        const bool valid = (n >= lo) && (n <= hi);
        f32x4 aq = acc[t4];
        float s0 = valid ? aq[0]*aq[0] : 0.f;
        float s1 = valid ? aq[1]*aq[1] : 0.f;
        float s2 = valid ? aq[2]*aq[2] : 0.f;
        float s3 = valid ? aq[3]*aq[3] : 0.f;
        #pragma unroll
        for (int off = 1; off <= 8; off <<= 1) {
            s0 += __shfl_xor(s0, off);
            s1 += __shfl_xor(s1, off);
            s2 += __shfl_xor(s2, off);
            s3 += __shfl_xor(s3, off);
        }
        const float sv = (n==0) ? s0 : ((n==1) ? s1 : ((n==2) ? s2 : s3));
        if (n < 4) {
            const int col = h*64 + t4*16 + g*4 + n;
            invg[(size_t)(rowbase + i)*LC + col] = sqrtf(sv + 1e-8f);
        }
    }
}

// ---------------- Kernel C1: partial pooling (64 blocks) ----------------
__global__ __launch_bounds__(128) void so3_pool(
    const float* __restrict__ invg,   // (B,N,128)
    float* __restrict__ pmax_p,       // (B,8,128)
    float* __restrict__ psum_p)       // (B,8,128)
{
    const int blk = blockIdx.x;
    const int b = blk >> 3;
    const int chunk = blk & 7;
    const int t = threadIdx.x;        // col
    const int ibase = b*NN + chunk*32;
    float mx = -1e30f, sm = 0.f;
    #pragma unroll 4
    for (int k = 0; k < 32; ++k) {
        const float v = invg[(size_t)(ibase + k)*LC + t];
        mx = fmaxf(mx, v);
        sm += v;
    }
    pmax_p[(size_t)blk*LC + t] = mx;
    psum_p[(size_t)blk*LC + t] = sm;
}

// ---------------- Kernel C2: combine + fc1 + LN + relu + fc2 ----------------
__global__ __launch_bounds__(512) void so3_post(
    const float* __restrict__ pmax_p, // (B,8,128)
    const float* __restrict__ psum_p, // (B,8,128)
    const float* __restrict__ fc1_w,  // (256,256)
    const float* __restrict__ fc1_b,  // (256)
    const float* __restrict__ ln_g,   // (256)
    const float* __restrict__ ln_b,   // (256)
    const float* __restrict__ fc2_w,  // (256,40)
    const float* __restrict__ fc2_b,  // (40)
    float* __restrict__ outg)         // (B,40)
{
    const int b = blockIdx.x;
    const int t = threadIdx.x;
    __shared__ float pooled[256];
    __shared__ float pfc1[2][256];
    __shared__ float h1s[256];
    __shared__ float pf2[8][40];
    __shared__ float redA[8], redB[8];

    if (t < 128) {
        float m0 = pmax_p[(size_t)(b*8)*LC + t];
        #pragma unroll
        for (int k = 1; k < 8; ++k) m0 = fmaxf(m0, pmax_p[(size_t)(b*8 + k)*LC + t]);
        pooled[t] = m0;
    } else if (t < 256) {
        const int lc = t - 128;
        float s0 = psum_p[(size_t)(b*8)*LC + lc];
        #pragma unroll
        for (int k = 1; k < 8; ++k) s0 += psum_p[(size_t)(b*8 + k)*LC + lc];
        pooled[t] = s0 * (1.f/256.f);
    }
    __syncthreads();

    {
        const int o = t & 255, kh = t >> 8;
        float acc = 0.f;
        for (int k = kh*128; k < kh*128 + 128; ++k)
            acc += pooled[k] * fc1_w[k*256 + o];
        pfc1[kh][o] = acc;
    }
    __syncthreads();

    float hval = 0.f;
    if (t < 256) hval = pfc1[0][t] + pfc1[1][t] + fc1_b[t];

    const int lane = t & 63, wid = t >> 6;
    float s1 = (t < 256) ? hval : 0.f;
    float s2 = (t < 256) ? hval*hval : 0.f;
    #pragma unroll
    for (int off = 32; off >= 1; off >>= 1) {
        s1 += __shfl_xor(s1, off);
        s2 += __shfl_xor(s2, off);
    }
    if (lane == 0) { redA[wid] = s1; redB[wid] = s2; }
    __syncthreads();
    s1 = redA[0]+redA[1]+redA[2]+redA[3];
    s2 = redB[0]+redB[1]+redB[2]+redB[3];
    if (t < 256) {
        const float mu = s1 * (1.f/256.f);
        const float var = s2 * (1.f/256.f) - mu*mu;
        float v = (hval - mu) * rsqrtf(var + 1e-5f) * ln_g[t] + ln_b[t];
        h1s[t] = fmaxf(v, 0.f);
    }
    __syncthreads();

    if (t < 320) {
        const int o = t % 40, ks = t / 40;
        float acc = 0.f;
        for (int k = ks*32; k < ks*32 + 32; ++k)
            acc += h1s[k] * fc2_w[k*40 + o];
        pf2[ks][o] = acc;
    }
    __syncthreads();
    if (t < 40) {
        float o = fc2_b[t];
        #pragma unroll
        for (int ks = 0; ks < 8; ++ks) o += pf2[ks][t];
        outg[b*40 + t] = o;
    }
}

extern "C" void kernel_launch(void* const* d_in, const int* in_sizes, int n_in,
                              void* d_out, int out_size, void* d_ws, size_t ws_size,
                              hipStream_t stream) {
    const float* x     = (const float*)d_in[0];
    const float* Wq    = (const float*)d_in[1];
    const float* Wk    = (const float*)d_in[2];
    const float* Wv    = (const float*)d_in[3];
    const float* Rw1   = (const float*)d_in[4];
    const float* Rb1   = (const float*)d_in[5];
    const float* Rw2   = (const float*)d_in[6];
    const float* Rb2   = (const float*)d_in[7];
    const float* fc1_w = (const float*)d_in[8];
    const float* fc1_b = (const float*)d_in[9];
    const float* ln_g  = (const float*)d_in[10];
    const float* ln_b  = (const float*)d_in[11];
    const float* fc2_w = (const float*)d_in[12];
    const float* fc2_b = (const float*)d_in[13];
    float* out = (float*)d_out;

    float* ws = (float*)d_ws;
    float* invg   = ws;                    // B*N*128 = 262144 f32
    float* pmax_p = invg + BB*NN*LC;       // 8192 f32
    float* psum_p = pmax_p + BB*8*LC;      // 8192 f32

    so3_main<<<BB*128, 256, 0, stream>>>(x, Wq, Wk, Wv, Rw1, Rb1, Rw2, Rb2, invg);
    so3_pool<<<BB*8, 128, 0, stream>>>(invg, pmax_p, psum_p);
    so3_post<<<BB, 512, 0, stream>>>(pmax_p, psum_p, fc1_w, fc1_b, ln_g, ln_b, fc2_w, fc2_b, out);
}

// Round 21
// 36.504 us; speedup vs baseline: 1.0854x; 1.0854x over previous
//
#include <hip/hip_runtime.h>
#include <hip/hip_bf16.h>

#define BB 8
#define NN 256
#define LC 128

typedef short short8 __attribute__((ext_vector_type(8)));
typedef float f32x4 __attribute__((ext_vector_type(4)));

union U8 { short8 s; unsigned u[4]; };

__device__ inline unsigned pkbf(float a, float b){
    __hip_bfloat162 h = __float22bfloat162_rn(make_float2(a, b));
    union { __hip_bfloat162 h2; unsigned u; } cv; cv.h2 = h; return cv.u;
}

// stage alpha*Y (bf16) for one j into a per-wave slab [msl][j], stride 264
__device__ inline void stage_aY(short* __restrict__ slab, int j, float a,
                                float dx, float dy, float dz, float r2)
{
    const float ir = rsqrtf(r2);
    const float ux = dx*ir, uy = dy*ir, uz = dz*ir;
    const float X2 = ux*ux, Y2 = uy*uy, Z2 = uz*uz;
    const float y0  = 0.28209479f;
    const float y1  = 0.48860251f*uy, y2 = 0.48860251f*uz, y3 = 0.48860251f*ux;
    const float y4  = 1.09254843f*ux*uy;
    const float y5  = 1.09254843f*uy*uz;
    const float y6  = 0.31539157f*(3.f*Z2 - 1.f);
    const float y7  = 1.09254843f*ux*uz;
    const float y8  = 0.54627422f*(X2 - Y2);
    const float y9  = 0.59004359f*uy*(3.f*X2 - Y2);
    const float y10 = 2.89061144f*ux*uy*uz;
    const float y11 = 0.45704579f*uy*(5.f*Z2 - 1.f);
    const float y12 = 0.37317633f*uz*(5.f*Z2 - 3.f);
    const float y13 = 0.45704579f*ux*(5.f*Z2 - 1.f);
    const float y14 = 1.44530572f*uz*(X2 - Y2);
    const float y15 = 0.59004359f*ux*(X2 - 3.f*Y2);
    #define ST2(mm, va, vb) { unsigned uu = pkbf((va)*a, (vb)*a); \
        slab[(mm)*264 + j] = (short)(uu & 0xffff); slab[(mm+1)*264 + j] = (short)(uu >> 16); }
    ST2(0,  y0,  y1)  ST2(2,  y2,  y3)
    ST2(4,  y4,  y5)  ST2(6,  y6,  y7)
    ST2(8,  y8,  y9)  ST2(10, y10, y11)
    ST2(12, y12, y13) ST2(14, y14, y15)
    #undef ST2
}

// ---------------- Kernel B: per-wave-independent main (R15/R19, 37.4us-proven) ----------------
// grid = BB*64 blocks; block = 4 waves; wave w owns i = (blk&63)*4 + w completely.
__global__ __launch_bounds__(256) void so3_main(
    const float* __restrict__ xg,     // (B,N,4)
    const float* __restrict__ Wq,     // (4,32)
    const float* __restrict__ Wk,     // (4,32)
    const float* __restrict__ Wv,     // (L,4,32)
    const float* __restrict__ Rw1,    // (32)
    const float* __restrict__ Rb1,    // (32)
    const float* __restrict__ Rw2,    // (32,128)
    const float* __restrict__ Rb2,    // (128)
    float* __restrict__ invg)         // (B,N,128)
{
    const int tid = threadIdx.x;          // 0..255
    const int blk = blockIdx.x;
    const int b = blk >> 6;
    const int iq = blk & 63;
    const int rowbase = b * NN;
    const int lane = tid & 63;
    const int w = tid >> 6;               // wave id; i = iq*4 + w
    const int n = lane & 15;
    const int g = lane >> 4;
    const int kbase = g * 8;
    const int i = iq*4 + w;

    __shared__ __align__(16) float xs[NN*4];     // 4 KB f32 x rows
    __shared__ short xsbf[NN*4];                 // 2 KB bf16 x rows
    __shared__ short aYs[4][16*264];             // per-wave alpha*Y slabs (33.8 KB)
    __shared__ float asum[4][256];               // per-wave alpha exchange / ssum scratch (4 KB)

    // ---- block-cooperative x staging (one row per thread) ----
    const float4 x4 = *(const float4*)&xg[(rowbase + tid)*4];
    *(float4*)&xs[tid*4] = x4;
    {
        uint2 xb;
        xb.x = pkbf(x4.x, x4.y);
        xb.y = pkbf(x4.z, x4.w);
        *(uint2*)&xsbf[tid*4] = xb;
    }
    const float4 xi = *(const float4*)&xg[(rowbase + i)*4];

    // ---- per-wave m[d] (shfl only) ----
    float md0, md1, md2, md3;
    {
        const int c = lane & 31;
        const float qc = xi.x*Wq[c] + xi.y*Wq[32+c] + xi.z*Wq[64+c] + xi.w*Wq[96+c];
        md0 = qc*Wk[c]; md1 = qc*Wk[32+c]; md2 = qc*Wk[64+c]; md3 = qc*Wk[96+c];
        #pragma unroll
        for (int off = 16; off >= 1; off >>= 1) {
            md0 += __shfl_xor(md0, off);
            md1 += __shfl_xor(md1, off);
            md2 += __shfl_xor(md2, off);
            md3 += __shfl_xor(md3, off);
        }
        const float lscale = 0.17677669529663687f;  // 1/sqrt(32)
        md0 *= lscale; md1 *= lscale; md2 *= lscale; md3 *= lscale;
    }

    __syncthreads();   // the ONLY block barrier: xs/xsbf ready

    // ---- per-lane sweep: r and logits for j = 16s+n (covers all 256 j per wave) ----
    float r_reg[16], lgv[16];
    #pragma unroll
    for (int s = 0; s < 16; ++s) {
        const float4 xa = *(const float4*)&xs[(16*s + n)*4];
        const float ddx = xa.x - xi.x, ddy = xa.y - xi.y, ddz = xa.z - xi.z;
        const float r2 = ddx*ddx + ddy*ddy + ddz*ddz + 1e-8f;
        r_reg[s] = sqrtf(r2);
        lgv[s] = md0*xa.x + md1*xa.y + md2*xa.z + md3*xa.w;
    }

    // ---- per-wave softmax ----
    float mx = lgv[0];
    #pragma unroll
    for (int s = 1; s < 16; ++s) mx = fmaxf(mx, lgv[s]);
    #pragma unroll
    for (int off = 1; off <= 8; off <<= 1) mx = fmaxf(mx, __shfl_xor(mx, off));
    float es = 0.f;
    float ev[16];
    #pragma unroll
    for (int s = 0; s < 16; ++s) { ev[s] = __expf(lgv[s] - mx); es += ev[s]; }
    #pragma unroll
    for (int off = 1; off <= 8; off <<= 1) es += __shfl_xor(es, off);
    const float invS = 1.0f / es;
    #pragma unroll
    for (int s = 0; s < 16; ++s) asum[w][16*s + n] = ev[s]*invS;

    asm volatile("s_waitcnt lgkmcnt(0)" ::: "memory");
    __builtin_amdgcn_sched_barrier(0);

    // ---- per-wave aY staging: lane (n,g) stages j = 64g + 16e + n ----
    short* slab = &aYs[w][0];
    #pragma unroll
    for (int e = 0; e < 4; ++e) {
        const int j = 64*g + 16*e + n;
        const float a = asum[w][j];
        const float4 xa = *(const float4*)&xs[j*4];
        const float ddx = xa.x - xi.x, ddy = xa.y - xi.y, ddz = xa.z - xi.z;
        const float r2 = ddx*ddx + ddy*ddy + ddz*ddz + 1e-8f;
        stage_aY(slab, j, a, ddx, ddy, ddz, r2);
    }

    float rw1q[8], rb1q[8];
    #pragma unroll
    for (int q = 0; q < 8; ++q) { rw1q[q] = Rw1[kbase+q]; rb1q[q] = Rb1[kbase+q]; }

    asm volatile("s_waitcnt lgkmcnt(0)" ::: "memory");
    __builtin_amdgcn_sched_barrier(0);

    const int boff = n*264 + 4*g;
    const f32x4 vzero = {0.f, 0.f, 0.f, 0.f};

    // ---- main loop: 2 col-halves x 8 j-tiles, barrier-free, per-wave ----
    #pragma unroll
    for (int h4 = 0; h4 < 2; ++h4) {
        short8 bfrag[4], bv[4];
        float rb2v[4];
        #pragma unroll
        for (int t4 = 0; t4 < 4; ++t4) {
            const int col = h4*64 + t4*16 + n;
            U8 bf;
            #pragma unroll
            for (int qq = 0; qq < 4; ++qq)
                bf.u[qq] = pkbf(Rw2[(kbase+2*qq)*LC + col], Rw2[(kbase+2*qq+1)*LC + col]);
            bfrag[t4] = bf.s;
            rb2v[t4] = Rb2[col];
            U8 z; z.u[0] = 0; z.u[1] = 0; z.u[2] = 0; z.u[3] = 0;
            if (g == 0) {
                const int l = (h4*64 + t4*16) >> 5;
                const int cc = (t4 & 1)*16 + n;
                z.u[0] = pkbf(Wv[l*128 + cc],      Wv[l*128 + 32 + cc]);
                z.u[1] = pkbf(Wv[l*128 + 64 + cc], Wv[l*128 + 96 + cc]);
            }
            bv[t4] = z.s;
        }

        f32x4 acc[4] = {};

        #pragma unroll
        for (int tt = 0; tt < 8; ++tt) {
            const int j0 = 32*tt;

            const uint2 blo = *(const uint2*)&slab[boff + j0];
            const uint2 bhi = *(const uint2*)&slab[boff + j0 + 16];
            U8 bf2;
            bf2.u[0] = blo.x; bf2.u[1] = blo.y; bf2.u[2] = bhi.x; bf2.u[3] = bhi.y;

            uint2 P[2][4];
            #pragma unroll
            for (int jh = 0; jh < 2; ++jh) {
                const float rj = r_reg[2*tt + jh];
                U8 af;
                #pragma unroll
                for (int qq = 0; qq < 4; ++qq) {
                    const float h0 = fmaxf(rj*rw1q[2*qq]   + rb1q[2*qq],   0.f);
                    const float h1 = fmaxf(rj*rw1q[2*qq+1] + rb1q[2*qq+1], 0.f);
                    af.u[qq] = pkbf(h0, h1);
                }
                U8 afV; afV.u[0] = 0; afV.u[1] = 0; afV.u[2] = 0; afV.u[3] = 0;
                if (g == 0) {
                    const uint2 xb = *(const uint2*)&xsbf[(j0 + 16*jh + n)*4];
                    afV.u[0] = xb.x; afV.u[1] = xb.y;
                }
                #pragma unroll
                for (int t4 = 0; t4 < 4; ++t4) {
                    f32x4 d  = __builtin_amdgcn_mfma_f32_16x16x32_bf16(af.s,  bfrag[t4], vzero, 0, 0, 0);
                    f32x4 vv = __builtin_amdgcn_mfma_f32_16x16x32_bf16(afV.s, bv[t4],    vzero, 0, 0, 0);
                    P[jh][t4].x = pkbf((d[0]+rb2v[t4])*vv[0], (d[1]+rb2v[t4])*vv[1]);
                    P[jh][t4].y = pkbf((d[2]+rb2v[t4])*vv[2], (d[3]+rb2v[t4])*vv[3]);
                }
            }

            #pragma unroll
            for (int t4 = 0; t4 < 4; ++t4) {
                U8 a2;
                a2.u[0] = P[0][t4].x; a2.u[1] = P[0][t4].y;
                a2.u[2] = P[1][t4].x; a2.u[3] = P[1][t4].y;
                acc[t4] = __builtin_amdgcn_mfma_f32_16x16x32_bf16(a2.s, bf2.s, acc[t4], 0, 0, 0);
            }
        }

        // ---- per-wave epilogue for this col-half ----
        #pragma unroll
        for (int t4 = 0; t4 < 4; ++t4) {
            const int l = h4*2 + (t4 >> 1);
            const int lo = l*l, hi = l*l + 2*l;
            const bool valid = (n >= lo) && (n <= hi);
            f32x4 aq = acc[t4];
            float s0 = valid ? aq[0]*aq[0] : 0.f;
            float s1 = valid ? aq[1]*aq[1] : 0.f;
            float s2 = valid ? aq[2]*aq[2] : 0.f;
            float s3 = valid ? aq[3]*aq[3] : 0.f;
            #pragma unroll
            for (int off = 1; off <= 8; off <<= 1) {
                s0 += __shfl_xor(s0, off);
                s1 += __shfl_xor(s1, off);
                s2 += __shfl_xor(s2, off);
                s3 += __shfl_xor(s3, off);
            }
            const float sv = (n==0) ? s0 : ((n==1) ? s1 : ((n==2) ? s2 : s3));
            if (n < 4) asum[w][h4*64 + t4*16 + g*4 + n] = sv;
        }
    }

    asm volatile("s_waitcnt lgkmcnt(0)" ::: "memory");
    __builtin_amdgcn_sched_barrier(0);
    {
        const float v0 = asum[w][lane];
        const float v1 = asum[w][lane + 64];
        float* dst = &invg[(size_t)(rowbase + i)*LC];
        dst[lane]      = sqrtf(v0 + 1e-8f);
        dst[lane + 64] = sqrtf(v1 + 1e-8f);
    }
}

// ---------------- Kernel C1: partial pooling (256 blocks, 8 rows each) ----------------
// blk = b*32 + chunk; 128 threads; i in [chunk*8, chunk*8+8)
__global__ __launch_bounds__(128) void so3_pool(
    const float* __restrict__ invg,   // (B,N,128)
    float* __restrict__ pmax_p,       // (B,32,128)
    float* __restrict__ psum_p)       // (B,32,128)
{
    const int blk = blockIdx.x;
    const int b = blk >> 5;
    const int chunk = blk & 31;
    const int t = threadIdx.x;        // col
    const int ibase = b*NN + chunk*8;
    float mx = -1e30f, sm = 0.f;
    #pragma unroll
    for (int k = 0; k < 8; ++k) {
        const float v = invg[(size_t)(ibase + k)*LC + t];
        mx = fmaxf(mx, v);
        sm += v;
    }
    pmax_p[(size_t)blk*LC + t] = mx;
    psum_p[(size_t)blk*LC + t] = sm;
}

// ---------------- Kernel C2: combine + fc1 + LN + relu + fc2 ----------------
__global__ __launch_bounds__(512) void so3_post(
    const float* __restrict__ pmax_p, // (B,32,128)
    const float* __restrict__ psum_p, // (B,32,128)
    const float* __restrict__ fc1_w,  // (256,256)
    const float* __restrict__ fc1_b,  // (256)
    const float* __restrict__ ln_g,   // (256)
    const float* __restrict__ ln_b,   // (256)
    const float* __restrict__ fc2_w,  // (256,40)
    const float* __restrict__ fc2_b,  // (40)
    float* __restrict__ outg)         // (B,40)
{
    const int b = blockIdx.x;
    const int t = threadIdx.x;
    __shared__ float pooled[256];
    __shared__ float pfc1[2][256];
    __shared__ float h1s[256];
    __shared__ float pf2[8][40];
    __shared__ float redA[8], redB[8];

    if (t < 128) {
        float m0 = pmax_p[(size_t)(b*32)*LC + t];
        #pragma unroll
        for (int k = 1; k < 32; ++k) m0 = fmaxf(m0, pmax_p[(size_t)(b*32 + k)*LC + t]);
        pooled[t] = m0;
    } else if (t < 256) {
        const int lc = t - 128;
        float s0 = psum_p[(size_t)(b*32)*LC + lc];
        #pragma unroll
        for (int k = 1; k < 32; ++k) s0 += psum_p[(size_t)(b*32 + k)*LC + lc];
        pooled[t] = s0 * (1.f/256.f);
    }
    __syncthreads();

    {
        const int o = t & 255, kh = t >> 8;
        float acc = 0.f;
        for (int k = kh*128; k < kh*128 + 128; ++k)
            acc += pooled[k] * fc1_w[k*256 + o];
        pfc1[kh][o] = acc;
    }
    __syncthreads();

    float hval = 0.f;
    if (t < 256) hval = pfc1[0][t] + pfc1[1][t] + fc1_b[t];

    const int lane = t & 63, wid = t >> 6;
    float s1 = (t < 256) ? hval : 0.f;
    float s2 = (t < 256) ? hval*hval : 0.f;
    #pragma unroll
    for (int off = 32; off >= 1; off >>= 1) {
        s1 += __shfl_xor(s1, off);
        s2 += __shfl_xor(s2, off);
    }
    if (lane == 0) { redA[wid] = s1; redB[wid] = s2; }
    __syncthreads();
    s1 = redA[0]+redA[1]+redA[2]+redA[3];
    s2 = redB[0]+redB[1]+redB[2]+redB[3];
    if (t < 256) {
        const float mu = s1 * (1.f/256.f);
        const float var = s2 * (1.f/256.f) - mu*mu;
        float v = (hval - mu) * rsqrtf(var + 1e-5f) * ln_g[t] + ln_b[t];
        h1s[t] = fmaxf(v, 0.f);
    }
    __syncthreads();

    if (t < 320) {
        const int o = t % 40, ks = t / 40;
        float acc = 0.f;
        for (int k = ks*32; k < ks*32 + 32; ++k)
            acc += h1s[k] * fc2_w[k*40 + o];
        pf2[ks][o] = acc;
    }
    __syncthreads();
    if (t < 40) {
        float o = fc2_b[t];
        #pragma unroll
        for (int ks = 0; ks < 8; ++ks) o += pf2[ks][t];
        outg[b*40 + t] = o;
    }
}

extern "C" void kernel_launch(void* const* d_in, const int* in_sizes, int n_in,
                              void* d_out, int out_size, void* d_ws, size_t ws_size,
                              hipStream_t stream) {
    const float* x     = (const float*)d_in[0];
    const float* Wq    = (const float*)d_in[1];
    const float* Wk    = (const float*)d_in[2];
    const float* Wv    = (const float*)d_in[3];
    const float* Rw1   = (const float*)d_in[4];
    const float* Rb1   = (const float*)d_in[5];
    const float* Rw2   = (const float*)d_in[6];
    const float* Rb2   = (const float*)d_in[7];
    const float* fc1_w = (const float*)d_in[8];
    const float* fc1_b = (const float*)d_in[9];
    const float* ln_g  = (const float*)d_in[10];
    const float* ln_b  = (const float*)d_in[11];
    const float* fc2_w = (const float*)d_in[12];
    const float* fc2_b = (const float*)d_in[13];
    float* out = (float*)d_out;

    float* ws = (float*)d_ws;
    float* invg   = ws;                    // B*N*128 = 262144 f32
    float* pmax_p = invg + BB*NN*LC;       // B*32*128 = 32768 f32
    float* psum_p = pmax_p + BB*32*LC;     // 32768 f32

    so3_main<<<BB*64, 256, 0, stream>>>(x, Wq, Wk, Wv, Rw1, Rb1, Rw2, Rb2, invg);
    so3_pool<<<BB*32, 128, 0, stream>>>(invg, pmax_p, psum_p);
    so3_post<<<BB, 512, 0, stream>>>(pmax_p, psum_p, fc1_w, fc1_b, ln_g, ln_b, fc2_w, fc2_b, out);
}